// Round 16
// baseline (521.998 us; speedup 1.0000x reference)
//
#include <hip/hip_runtime.h>
#include <stdint.h>

typedef unsigned short u16;
typedef uint32_t u32;

typedef __bf16 bf16x8 __attribute__((ext_vector_type(8)));
typedef float f32x4 __attribute__((ext_vector_type(4)));
typedef _Float16 h2v __attribute__((ext_vector_type(2)));

union B8 { uint4 q; u32 u[4]; bf16x8 v; };

__device__ __forceinline__ u16 f2bf(float f) {
  u32 u = __float_as_uint(f);
  u32 r = (u + 0x7fffu + ((u >> 16) & 1u)) >> 16;
  return (u16)r;
}
__device__ __forceinline__ u16 f2h(float f) {
  union { _Float16 h; u16 u; } v; v.h = (_Float16)f; return v.u;
}
__device__ __forceinline__ float dot2h(u32 a, u32 b, float c) {
  union U { u32 u; h2v v; } A, B; A.u = a; B.u = b;
  return __builtin_amdgcn_fdot2(A.v, B.v, c, false);
}
__device__ __forceinline__ float sigf(float x) { return 1.f / (1.f + __expf(-x)); }
__device__ __forceinline__ float tanhf_fast(float x) {
  x = fminf(fmaxf(x, -15.f), 15.f);
  float e = __expf(2.f * x);
  return (e - 1.f) / (e + 1.f);
}

// ---------------- prep: pack/convert all weights (grid-stride x4) ----------------
__device__ __forceinline__ void prep_one(int e,
    const float* rnn_w_hh, const float* dec_w_hh, const float* conv1_w,
    const float* conv2_w, const float* rnn_w_ih, const float* dec_w_ih,
    const float* fc_w, const float* emb, const int* y,
    u32* wT2e, u32* wT2d, u16* w1b, u16* w2b, u16* wihb, u16* dwihb,
    u16* fcwb, u16* adec)
{
  const int S0 = 24576, S1 = 24576, S2 = 5120, S3 = 163840, S4 = 208896,
            S5 = 12288, S6 = 524288, S7 = 130048;
  if (e < S0) { int g = e >> 6, k2 = e & 63;
    wT2e[e] = (u32)f2h(rnn_w_hh[g*128 + 2*k2]) | ((u32)f2h(rnn_w_hh[g*128 + 2*k2 + 1]) << 16);
    return; }
  e -= S0;
  if (e < S1) { int g = e >> 6, k2 = e & 63;
    wT2d[e] = (u32)f2h(dec_w_hh[g*128 + 2*k2]) | ((u32)f2h(dec_w_hh[g*128 + 2*k2 + 1]) << 16);
    return; }
  e -= S1;
  if (e < S2) { int kh = e >> 10, c = (e >> 5) & 31, kw = e & 31;
    w1b[e] = f2bf(conv1_w[c*160 + kh*32 + kw]); return; }
  e -= S2;
  if (e < S3) { int kt = e >> 10, c = (e >> 5) & 31, kw = e & 31;
    int ic = kt / 5, kh = kt - ic * 5;
    w2b[e] = f2bf(conv2_w[((c*32 + ic)*5 + kh)*32 + kw]); return; }
  e -= S3;
  if (e < S4) { wihb[e] = f2bf(rnn_w_ih[e]); return; }
  e -= S4;
  if (e < S5) { dwihb[e] = f2bf(dec_w_ih[e]); return; }
  e -= S5;
  if (e < S6) { fcwb[e] = f2bf(fc_w[e]); return; }
  e -= S6;
  if (e < S7) { int m = e >> 5, k = e & 31;
    int b = m / 127, t = m - b * 127;
    adec[e] = f2bf(emb[y[b*128 + t]*32 + k]); return; }
}

__global__ __launch_bounds__(256) void prep_k(
    const float* rnn_w_hh, const float* dec_w_hh, const float* conv1_w,
    const float* conv2_w, const float* rnn_w_ih, const float* dec_w_ih,
    const float* fc_w, const float* emb, const int* y,
    u32* wT2e, u32* wT2d, u16* w1b, u16* w2b, u16* wihb, u16* dwihb,
    u16* fcwb, u16* adec)
{
  int e0 = blockIdx.x * 256 + threadIdx.x;
  #pragma unroll
  for (int it = 0; it < 4; it++) {
    int e = e0 + it * 273408;
    if (e < 1093632)
      prep_one(e, rnn_w_hh, dec_w_hh, conv1_w, conv2_w, rnn_w_ih, dec_w_ih,
               fc_w, emb, y, wT2e, wT2d, w1b, w2b, wihb, dwihb, fcwb, adec);
  }
}

// ---------------- conv1: (32,1,512,161) -> in1b (32,32,254,72pad) bf16, MFMA ----------------
__global__ __launch_bounds__(256) void conv1_k(const float* x, const u16* w1b,
                                               const float* c1b, u16* in1b)
{
  __shared__ __align__(16) u16 slab[35 * 162];
  __shared__ __align__(16) u16 wl[5120];
  int b = blockIdx.x >> 4;
  int oh0 = (blockIdx.x & 15) * 16;
  int ih0 = oh0 * 2;
  for (int e = threadIdx.x; e < 35 * 161; e += 256) {
    int r = e / 161, iw = e - r * 161;
    int ih = ih0 + r;
    float v = (ih < 512) ? x[(b*512 + ih)*161 + iw] : 0.f;
    slab[r*162 + iw] = f2bf(v);
  }
  for (int e = threadIdx.x; e < 5120; e += 256) wl[e] = w1b[e];
  __syncthreads();
  int lane = threadIdx.x & 63, wid = threadIdx.x >> 6;
  int lrow = lane & 15, lk = (lane >> 4) * 8;
  B8 bw[5][2];
  #pragma unroll
  for (int kt = 0; kt < 5; kt++)
    #pragma unroll
    for (int ct = 0; ct < 2; ct++)
      bw[kt][ct].q = *(const uint4*)&wl[(kt*32 + ct*16 + lrow)*32 + lk];
  float bias0 = c1b[lrow], bias1 = c1b[16 + lrow];
  for (int mt = wid; mt < 65; mt += 4) {
    int m = mt * 16 + lrow;
    int ohl = m / 65, ow = m - ohl * 65;
    int ro = ohl * 324 + ow * 2 + lk;
    f32x4 a0, a1;
    #pragma unroll
    for (int i = 0; i < 4; i++) { a0[i] = 0.f; a1[i] = 0.f; }
    #pragma unroll
    for (int kt = 0; kt < 5; kt++) {
      B8 af;
      const u32* p = (const u32*)&slab[ro + kt * 162];
      af.u[0] = p[0]; af.u[1] = p[1]; af.u[2] = p[2]; af.u[3] = p[3];
      a0 = __builtin_amdgcn_mfma_f32_16x16x32_bf16(af.v, bw[kt][0].v, a0, 0, 0, 0);
      a1 = __builtin_amdgcn_mfma_f32_16x16x32_bf16(af.v, bw[kt][1].v, a1, 0, 0, 0);
    }
    int rb = mt * 16 + (lane >> 4) * 4;
    #pragma unroll
    for (int i = 0; i < 4; i++) {
      int mr = rb + i;
      int ohl2 = mr / 65, ow2 = mr - ohl2 * 65;
      int oh = oh0 + ohl2;
      if (oh < 254) {
        float v0 = fmaxf(a0[i] + bias0, 0.f);
        float v1 = fmaxf(a1[i] + bias1, 0.f);
        in1b[((b*32 + lrow)*254 + oh)*72 + ow2] = f2bf(v0);
        in1b[((b*32 + 16 + lrow)*254 + oh)*72 + ow2] = f2bf(v1);
      }
    }
  }
}

// ---------------- conv2: in1b (32,32,254,72) -> h (32,125,544) bf16, MFMA ----------------
__global__ __launch_bounds__(256) void conv2_k(const u16* in1b, const u16* w2b,
                                               const float* c2b, u16* hbf)
{
  extern __shared__ char smem[];
  u16* slab = (u16*)smem;              // [32][11][72]  = 50688 B
  u16* wl = (u16*)(smem + 50688);      // [10][32][32]  = 20480 B
  int b = blockIdx.x >> 5;
  int tile = blockIdx.x & 31;
  int oh0 = tile * 4;
  int ih0 = oh0 * 2;
  for (int q = threadIdx.x; q < 3168; q += 256) {
    int ic = q / 99;
    int rem = q - ic * 99;
    int r = rem / 9, j = rem - r * 9;
    int ih = ih0 + r;
    uint4 v = make_uint4(0u, 0u, 0u, 0u);
    if (ih < 254) v = *(const uint4*)&in1b[(((b*32 + ic)*254 + ih)*72) + j*8];
    *(uint4*)&slab[(ic*11 + r)*72 + j*8] = v;
  }
  int lane = threadIdx.x & 63, wid = threadIdx.x >> 6;
  int lrow = lane & 15, lk = (lane >> 4) * 8;
  int ohl_[2], ow_[2];
  #pragma unroll
  for (int q = 0; q < 2; q++) {
    int mt = (q == 1) ? 4 : wid;
    int m = mt * 16 + lrow;
    if (m > 67) m = 0;
    ohl_[q] = m / 17; ow_[q] = m - ohl_[q] * 17;
  }
  f32x4 acc[2][2];
  #pragma unroll
  for (int q = 0; q < 2; q++)
    #pragma unroll
    for (int ct = 0; ct < 2; ct++)
      #pragma unroll
      for (int i = 0; i < 4; i++) acc[q][ct][i] = 0.f;

  for (int ph = 0; ph < 16; ph++) {
    __syncthreads();
    {
      const uint4* s4 = (const uint4*)&w2b[ph * 10240];
      uint4* d4 = (uint4*)wl;
      for (int q = threadIdx.x; q < 1280; q += 256) d4[q] = s4[q];
    }
    __syncthreads();
    for (int ktl = 0; ktl < 10; ktl++) {
      int ktg = ph * 10 + ktl;
      int ic = ktg / 5, kh = ktg - ic * 5;
      B8 fb0, fb1;
      fb0.q = *(const uint4*)&wl[(ktl*32 + lrow)*32 + lk];
      fb1.q = *(const uint4*)&wl[(ktl*32 + 16 + lrow)*32 + lk];
      int base = (ic * 11 + kh) * 72 + lk;
      #pragma unroll
      for (int q = 0; q < 2; q++) {
        if (q == 1 && wid != 0) break;
        B8 af;
        const u32* p = (const u32*)&slab[base + ohl_[q] * 144 + ow_[q] * 2];
        af.u[0] = p[0]; af.u[1] = p[1]; af.u[2] = p[2]; af.u[3] = p[3];
        acc[q][0] = __builtin_amdgcn_mfma_f32_16x16x32_bf16(af.v, fb0.v, acc[q][0], 0, 0, 0);
        acc[q][1] = __builtin_amdgcn_mfma_f32_16x16x32_bf16(af.v, fb1.v, acc[q][1], 0, 0, 0);
      }
    }
  }
  #pragma unroll
  for (int q = 0; q < 2; q++) {
    if (q == 1 && wid != 0) break;
    int mt = (q == 1) ? 4 : wid;
    int rb = mt * 16 + (lane >> 4) * 4;
    #pragma unroll
    for (int ct = 0; ct < 2; ct++) {
      int c = ct * 16 + lrow;
      float bias = c2b[c];
      #pragma unroll
      for (int i = 0; i < 4; i++) {
        int mr = rb + i;
        if (mr < 68) {
          int ohl = mr / 17, ow = mr - ohl * 17;
          int oh = oh0 + ohl;
          if (oh < 125) {
            float v = fmaxf(acc[q][ct][i] + bias, 0.f);
            hbf[(b*125 + oh)*544 + ow*32 + c] = f2bf(v);
          }
        }
      }
    }
  }
}

// ---------------- generic bf16 MFMA GEMM: C = A(MxK) * B(NxK)^T + bias ----------------
__global__ __launch_bounds__(256) void gemm_k(const u16* A, const u16* Bw,
                                              const float* bias, float* C,
                                              int M, int N, int K)
{
  __shared__ __align__(16) u16 As[64 * 32];
  __shared__ __align__(16) u16 Bs[64 * 32];
  int m0 = blockIdx.x * 64, n0 = blockIdx.y * 64;
  int tid = threadIdx.x;
  int lane = tid & 63, wid = tid >> 6;
  int lrow = lane & 15, lk = (lane >> 4) * 8;
  int sr = tid >> 2, sc8 = (tid & 3) * 8;
  f32x4 acc[4];
  #pragma unroll
  for (int nt = 0; nt < 4; nt++)
    #pragma unroll
    for (int i = 0; i < 4; i++) acc[nt][i] = 0.f;
  int nkt = K >> 5;
  for (int kt = 0; kt < nkt; kt++) {
    __syncthreads();
    uint4 va = make_uint4(0u, 0u, 0u, 0u);
    int arow = m0 + sr;
    if (arow < M) va = *(const uint4*)&A[arow * K + kt * 32 + sc8];
    *(uint4*)&As[sr * 32 + sc8] = va;
    uint4 vb = *(const uint4*)&Bw[(n0 + sr) * K + kt * 32 + sc8];
    *(uint4*)&Bs[sr * 32 + sc8] = vb;
    __syncthreads();
    B8 af; af.q = *(const uint4*)&As[(wid * 16 + lrow) * 32 + lk];
    #pragma unroll
    for (int nt = 0; nt < 4; nt++) {
      B8 bb; bb.q = *(const uint4*)&Bs[(nt * 16 + lrow) * 32 + lk];
      acc[nt] = __builtin_amdgcn_mfma_f32_16x16x32_bf16(af.v, bb.v, acc[nt], 0, 0, 0);
    }
  }
  #pragma unroll
  for (int nt = 0; nt < 4; nt++) {
    int col = n0 + nt * 16 + lrow;
    float bv = bias[col];
    #pragma unroll
    for (int i = 0; i < 4; i++) {
      int row = m0 + wid * 16 + (lane >> 4) * 4 + i;
      if (row < M) C[row * N + col] = acc[nt][i] + bv;
    }
  }
}

// ---------------- fc GEMM: 4096x4096, K=128, 128x64 tile ----------------
__global__ __launch_bounds__(256) void fc_k(const u16* A, const u16* Bw,
                                            const float* bias, float* C)
{
  __shared__ __align__(16) u16 As[128 * 32];
  __shared__ __align__(16) u16 Bs[64 * 32];
  int m0 = blockIdx.x * 128, n0 = blockIdx.y * 64;
  int tid = threadIdx.x;
  int lane = tid & 63, wid = tid >> 6;
  int lrow = lane & 15, lk = (lane >> 4) * 8;
  f32x4 acc[2][4];
  #pragma unroll
  for (int mq = 0; mq < 2; mq++)
    #pragma unroll
    for (int nt = 0; nt < 4; nt++)
      #pragma unroll
      for (int i = 0; i < 4; i++) acc[mq][nt][i] = 0.f;
  #pragma unroll
  for (int kt = 0; kt < 4; kt++) {
    __syncthreads();
    #pragma unroll
    for (int i = tid; i < 512; i += 256) {
      int row = i >> 2, q = i & 3;
      *(uint4*)&As[row * 32 + q * 8] = *(const uint4*)&A[(m0 + row) * 128 + kt * 32 + q * 8];
    }
    {
      int row = tid >> 2, q = tid & 3;
      *(uint4*)&Bs[row * 32 + q * 8] = *(const uint4*)&Bw[(n0 + row) * 128 + kt * 32 + q * 8];
    }
    __syncthreads();
    B8 bb[4];
    #pragma unroll
    for (int nt = 0; nt < 4; nt++) bb[nt].q = *(const uint4*)&Bs[(nt * 16 + lrow) * 32 + lk];
    #pragma unroll
    for (int mq = 0; mq < 2; mq++) {
      B8 af; af.q = *(const uint4*)&As[((wid * 2 + mq) * 16 + lrow) * 32 + lk];
      #pragma unroll
      for (int nt = 0; nt < 4; nt++)
        acc[mq][nt] = __builtin_amdgcn_mfma_f32_16x16x32_bf16(af.v, bb[nt].v, acc[mq][nt], 0, 0, 0);
    }
  }
  #pragma unroll
  for (int nt = 0; nt < 4; nt++) {
    int col = n0 + nt * 16 + lrow;
    float bv = bias[col];
    #pragma unroll
    for (int mq = 0; mq < 2; mq++)
      #pragma unroll
      for (int i = 0; i < 4; i++) {
        int row = m0 + (wid * 2 + mq) * 16 + (lane >> 4) * 4 + i;
        C[(size_t)row * 4096 + col] = acc[mq][nt][i] + bv;
      }
  }
}

// ---------------- encoder GRU scan: 32 blocks, 512 thr, 1 batch, K-split 4 ----------------
__global__ __launch_bounds__(512, 1) void enc_k(const u32* wT2, const float* xg,
                                                const float* bhh_g, u16* ehk, u16* eht)
{
  __shared__ __align__(16) u32 hp[2][64];      // [buf][64]
  __shared__ float hg[1152];                   // [kh-1][gate][128]
  int tid = threadIdx.x;
  int kh = tid >> 7, t = tid & 127;
  int b = blockIdx.x;
  u32 w0[16], w1[16], w2[16];
  {
    const uint4* p0 = (const uint4*)(wT2 + (size_t)t * 64 + kh * 16);
    const uint4* p1 = (const uint4*)(wT2 + (size_t)(128 + t) * 64 + kh * 16);
    const uint4* p2 = (const uint4*)(wT2 + (size_t)(256 + t) * 64 + kh * 16);
    #pragma unroll
    for (int j = 0; j < 4; j++) {
      uint4 q0 = p0[j]; w0[4*j] = q0.x; w0[4*j+1] = q0.y; w0[4*j+2] = q0.z; w0[4*j+3] = q0.w;
      uint4 q1 = p1[j]; w1[4*j] = q1.x; w1[4*j+1] = q1.y; w1[4*j+2] = q1.z; w1[4*j+3] = q1.w;
      uint4 q2 = p2[j]; w2[4*j] = q2.x; w2[4*j+1] = q2.y; w2[4*j+2] = q2.z; w2[4*j+3] = q2.w;
    }
  }
  float b0 = 0.f, b1 = 0.f, b2 = 0.f, xr0 = 0.f, xr1 = 0.f, xr2 = 0.f, hreg = 0.f;
  if (kh == 0) {
    b0 = bhh_g[t]; b1 = bhh_g[128 + t]; b2 = bhh_g[256 + t];
    const float* xp = &xg[(size_t)b * 125 * 384];
    xr0 = xp[t]; xr1 = xp[128 + t]; xr2 = xp[256 + t];
    ((u16*)&hp[0][0])[t] = 0;
  }
  __syncthreads();
  for (int tt = 0; tt < 125; tt++) {
    const u32* hb = &hp[tt & 1][kh * 16];
    float r0 = 0.f, r1 = 0.f, z0 = 0.f, z1 = 0.f, n0 = 0.f, n1 = 0.f;
    #pragma unroll
    for (int j = 0; j < 4; j++) {
      uint4 hv = *(const uint4*)&hb[4*j];
      r0 = dot2h(w0[4*j+0], hv.x, r0); r1 = dot2h(w0[4*j+1], hv.y, r1);
      r0 = dot2h(w0[4*j+2], hv.z, r0); r1 = dot2h(w0[4*j+3], hv.w, r1);
      z0 = dot2h(w1[4*j+0], hv.x, z0); z1 = dot2h(w1[4*j+1], hv.y, z1);
      z0 = dot2h(w1[4*j+2], hv.z, z0); z1 = dot2h(w1[4*j+3], hv.w, z1);
      n0 = dot2h(w2[4*j+0], hv.x, n0); n1 = dot2h(w2[4*j+1], hv.y, n1);
      n0 = dot2h(w2[4*j+2], hv.z, n0); n1 = dot2h(w2[4*j+3], hv.w, n1);
    }
    if (kh) {
      float* hh = &hg[(kh - 1) * 384];
      hh[t] = r0 + r1; hh[128 + t] = z0 + z1; hh[256 + t] = n0 + n1;
    }
    __syncthreads();
    if (kh == 0) {
      const float* hh = &hg[0];
      float pr = r0 + r1 + hh[t] + hh[384 + t] + hh[768 + t];
      float pz = z0 + z1 + hh[128 + t] + hh[512 + t] + hh[896 + t];
      float pn = n0 + n1 + hh[256 + t] + hh[640 + t] + hh[1024 + t];
      float r = sigf(xr0 + pr + b0);
      float z = sigf(xr1 + pz + b1);
      float n = tanhf_fast(xr2 + r * (pn + b2));
      hreg = (1.f - z) * n + z * hreg;
      u16 hv = f2h(hreg);
      ((u16*)&hp[(tt & 1) ^ 1][0])[t] = hv;
      ehk[((size_t)(b*64 + (t >> 1)) * 125 + tt) * 2 + (t & 1)] = hv;
      eht[((size_t)(b*128 + t)) * 128 + tt] = hv;
      if (tt + 1 < 125) {
        const float* xq = &xg[((size_t)b * 125 + tt + 1) * 384];
        xr0 = xq[t]; xr1 = xq[128 + t]; xr2 = xq[256 + t];
      }
    }
    __syncthreads();
  }
  if (kh == 0) {
    size_t rb = ((size_t)(b*128 + t)) * 128;
    eht[rb + 125] = 0; eht[rb + 126] = 0; eht[rb + 127] = 0;
  }
}

// ---------------- decoder GRU + attention: 32 blocks, 256 thr, 1 batch, K-split 2 ----------------
// Same phase skeleton; barrier scope 4 waves. Persistent regs: 96 w + 32 rowr.
// LDS (35856 B): elK 32000 | hgP 1536 | sp 1024 | ctxB 512 | hxA/hxB/scp 768 | red 16
__global__ __launch_bounds__(256, 1) __attribute__((amdgpu_waves_per_eu(1)))
void dec_k(const u32* wT2, const u32* ehk_g, const u32* eht_g, const float* xgd,
           const float* bhh_g, const float* h_init, u16* outb)
{
  extern __shared__ char sm[];
  int tid = threadIdx.x;
  int kh = tid >> 7, t = tid & 127;   // kh in {0,1}
  int b = blockIdx.x;
  u32* elK   = (u32*)sm;                      // [64][125]
  float* hgP = (float*)(sm + 32000);          // [3][128] (kh1 partials)
  float* sp  = (float*)(sm + 33536);          // [2][128]
  float* ctxB= (float*)(sm + 34560);          // [128]
  u16* hxA   = (u16*)(sm + 35072);
  u16* hxB   = (u16*)(sm + 35328);
  u16* scp   = (u16*)(sm + 35584);
  float* red = (float*)(sm + 35840);

  u32 w0[32], w1[32], w2[32];
  {
    const uint4* p0 = (const uint4*)(wT2 + (size_t)t * 64 + kh * 32);
    const uint4* p1 = (const uint4*)(wT2 + (size_t)(128 + t) * 64 + kh * 32);
    const uint4* p2 = (const uint4*)(wT2 + (size_t)(256 + t) * 64 + kh * 32);
    #pragma unroll
    for (int j = 0; j < 8; j++) {
      uint4 q0 = p0[j]; w0[4*j] = q0.x; w0[4*j+1] = q0.y; w0[4*j+2] = q0.z; w0[4*j+3] = q0.w;
      uint4 q1 = p1[j]; w1[4*j] = q1.x; w1[4*j+1] = q1.y; w1[4*j+2] = q1.z; w1[4*j+3] = q1.w;
      uint4 q2 = p2[j]; w2[4*j] = q2.x; w2[4*j+1] = q2.y; w2[4*j+2] = q2.z; w2[4*j+3] = q2.w;
    }
  }
  // context operand: unit-row t, t-pair half kh of eh^T (step-constant, 32 u32)
  u32 rowr[32];
  {
    const uint4* rp = (const uint4*)(eht_g + (size_t)b * 8192 + (size_t)t * 64 + kh * 32);
    #pragma unroll
    for (int j = 0; j < 8; j++) {
      uint4 q = rp[j];
      rowr[4*j] = q.x; rowr[4*j+1] = q.y; rowr[4*j+2] = q.z; rowr[4*j+3] = q.w;
    }
  }
  {
    const uint4* s4 = (const uint4*)(ehk_g + (size_t)b * 8000);
    uint4* d4 = (uint4*)elK;
    for (int q = tid; q < 2000; q += 256) d4[q] = s4[q];
  }
  float b0 = 0.f, b1 = 0.f, b2 = 0.f, xr0 = 0.f, xr1 = 0.f, xr2 = 0.f;
  float hxf = 0.f, hxg = 0.f;
  if (kh == 0) {
    b0 = bhh_g[t]; b1 = bhh_g[128 + t]; b2 = bhh_g[256 + t];
    hxf = h_init[t];
    const float* xp = &xgd[(size_t)b * 127 * 384];
    xr0 = xp[t]; xr1 = xp[128 + t]; xr2 = xp[256 + t];
  }
  __syncthreads();

  for (int step = 0; step < 128; step++) {
    if (step > 0) {
      // ---- S0: GRU half-K dots (all 256 thr) ----
      const u32* hb = (const u32*)hxB + kh * 32;
      float r0 = 0.f, r1 = 0.f, z0 = 0.f, z1 = 0.f, n0 = 0.f, n1 = 0.f;
      #pragma unroll
      for (int j = 0; j < 8; j++) {
        uint4 hv = *(const uint4*)&hb[4*j];
        r0 = dot2h(w0[4*j+0], hv.x, r0); r1 = dot2h(w0[4*j+1], hv.y, r1);
        r0 = dot2h(w0[4*j+2], hv.z, r0); r1 = dot2h(w0[4*j+3], hv.w, r1);
        z0 = dot2h(w1[4*j+0], hv.x, z0); z1 = dot2h(w1[4*j+1], hv.y, z1);
        z0 = dot2h(w1[4*j+2], hv.z, z0); z1 = dot2h(w1[4*j+3], hv.w, z1);
        n0 = dot2h(w2[4*j+0], hv.x, n0); n1 = dot2h(w2[4*j+1], hv.y, n1);
        n0 = dot2h(w2[4*j+2], hv.z, n0); n1 = dot2h(w2[4*j+3], hv.w, n1);
      }
      if (kh) {
        hgP[t] = r0 + r1; hgP[128 + t] = z0 + z1; hgP[256 + t] = n0 + n1;
      }
      __syncthreads();                       // bar1
      if (kh == 0) {
        float pr = r0 + r1 + hgP[t];
        float pz = z0 + z1 + hgP[128 + t];
        float pn = n0 + n1 + hgP[256 + t];
        float r = sigf(xr0 + pr + b0);
        float z = sigf(xr1 + pz + b1);
        float n = tanhf_fast(xr2 + r * (pn + b2));
        hxg = (1.f - z) * n + z * hxf;
        ((u16*)hxA)[t] = f2h(hxg);
        if (step < 127) {
          const float* xq = &xgd[((size_t)b * 127 + step) * 384];
          xr0 = xq[t]; xr1 = xq[128 + t]; xr2 = xq[256 + t];
        }
      }
      __syncthreads();                       // bar2
    } else {
      if (kh == 0) { hxg = hxf; ((u16*)hxA)[t] = f2h(hxg); }
      __syncthreads();                       // bar2
    }
    // ---- S2a: score half-K partials (all threads; t = time index) ----
    {
      float s0 = 0.f, s1 = 0.f;
      const u32* ek = &elK[(kh * 32) * 125];
      const u32* hxA4 = (const u32*)hxA;
      #pragma unroll
      for (int j = 0; j < 8; j++) {
        uint4 aw = *(const uint4*)&hxA4[kh * 32 + 4*j];
        s0 = dot2h(ek[(4*j+0)*125 + t], aw.x, s0);
        s1 = dot2h(ek[(4*j+1)*125 + t], aw.y, s1);
        s0 = dot2h(ek[(4*j+2)*125 + t], aw.z, s0);
        s1 = dot2h(ek[(4*j+3)*125 + t], aw.w, s1);
      }
      sp[kh * 128 + t] = s0 + s1;
    }
    __syncthreads();                         // bar3a
    // ---- S2b: combine + softmax (kh0; waves = t 0-63 / 64-127) ----
    if (kh == 0) {
      float s = (t < 125) ? (sp[t] + sp[128 + t]) : -1e30f;
      float mw = s;
      #pragma unroll
      for (int o = 32; o > 0; o >>= 1) mw = fmaxf(mw, __shfl_xor(mw, o));
      float ev = (t < 125) ? __expf(s - mw) : 0.f;
      float sw = ev;
      #pragma unroll
      for (int o = 32; o > 0; o >>= 1) sw += __shfl_xor(sw, o);
      ((u16*)scp)[t] = f2h(ev);
      if ((t & 63) == 0) { int wv = t >> 6; red[wv*2] = mw; red[wv*2 + 1] = sw; }
    }
    __syncthreads();                         // bar3
    // ---- S3: context half-T dots (all threads; t = unit index) ----
    float m0r = red[0], S0r = red[1], m1r = red[2], S1r = red[3];
    float M = fmaxf(m0r, m1r);
    float f0 = __expf(m0r - M), f1 = __expf(m1r - M);
    float inv = 1.f / (f0 * S0r + f1 * S1r);
    float c0 = 0.f, c1 = 0.f;
    {
      const u32* scp4 = (const u32*)scp;
      #pragma unroll
      for (int j = 0; j < 8; j++) {
        uint4 sw4 = *(const uint4*)&scp4[kh * 32 + 4*j];
        c0 = dot2h(rowr[4*j+0], sw4.x, c0); c1 = dot2h(rowr[4*j+1], sw4.y, c1);
        c0 = dot2h(rowr[4*j+2], sw4.z, c0); c1 = dot2h(rowr[4*j+3], sw4.w, c1);
      }
    }
    if (kh) ctxB[t] = c0 + c1;
    __syncthreads();                         // bar4
    if (kh == 0) {
      // kh0 covers t<64 (scale f0); kh1 covers t>=64 (f1)
      float ctx = (c0 + c1) * f0 + ctxB[t] * f1;
      hxf = hxg + ctx * inv;
      outb[((size_t)(b * 128) + step) * 128 + t] = f2bf(hxf);
      ((u16*)hxB)[t] = f2h(hxf);
    }
    __syncthreads();                         // bar5
  }
}

// ---------------- host launch ----------------
extern "C" void kernel_launch(void* const* d_in, const int* in_sizes, int n_in,
                              void* d_out, int out_size, void* d_ws, size_t ws_size,
                              hipStream_t stream)
{
  const float* x        = (const float*)d_in[0];
  const int*   y        = (const int*)d_in[1];
  const float* conv1_w  = (const float*)d_in[2];
  const float* conv1_b  = (const float*)d_in[3];
  const float* conv2_w  = (const float*)d_in[4];
  const float* conv2_b  = (const float*)d_in[5];
  const float* rnn_w_ih = (const float*)d_in[6];
  const float* rnn_w_hh = (const float*)d_in[7];
  const float* rnn_b_ih = (const float*)d_in[8];
  const float* rnn_b_hh = (const float*)d_in[9];
  const float* emb      = (const float*)d_in[10];
  const float* dec_w_ih = (const float*)d_in[11];
  const float* dec_w_hh = (const float*)d_in[12];
  const float* dec_b_ih = (const float*)d_in[13];
  const float* dec_b_hh = (const float*)d_in[14];
  const float* fc_w     = (const float*)d_in[15];
  const float* fc_b     = (const float*)d_in[16];
  const float* h_init   = (const float*)d_in[17];
  float* logits = (float*)d_out;

  char* ws = (char*)d_ws;
  size_t off = 0;
  auto alloc = [&](size_t bytes) { char* p = ws + off; off = (off + bytes + 255) & ~(size_t)255; return p; };
  u16* in1b  = (u16*)alloc(37453824);  // conv1 out bf16 (32,32,254,72pad)
  u16* hbf   = (u16*)alloc(4352000);   // h bf16 (4000,544)
  float* xge = (float*)alloc(6144000); // enc xg (4000,384)
  u32* ehb_k = (u32*)alloc(1024000);   // eh f16 k-pairs (32,64,125)
  u32* ehb_t = (u32*)alloc(1048576);   // eh f16 t-pair rows (32,128,64)
  float* xgd = (float*)alloc(6242304); // dec xg (4064,384)
  u16* adec  = (u16*)alloc(260096);    // emb gather (4064,32)
  u16* outb  = (u16*)alloc(1048576);   // decoder out bf16 (4096,128)
  u32* wT2e  = (u32*)alloc(98304);
  u32* wT2d  = (u32*)alloc(98304);
  u16* w1b   = (u16*)alloc(10240);
  u16* w2b   = (u16*)alloc(327680);
  u16* wihb  = (u16*)alloc(417792);
  u16* dwihb = (u16*)alloc(24576);
  u16* fcwb  = (u16*)alloc(1048576);

  hipFuncSetAttribute((const void*)conv2_k, hipFuncAttributeMaxDynamicSharedMemorySize, 71168);
  hipFuncSetAttribute((const void*)dec_k,   hipFuncAttributeMaxDynamicSharedMemorySize, 35856);

  prep_k<<<1068, 256, 0, stream>>>(rnn_w_hh, dec_w_hh, conv1_w, conv2_w, rnn_w_ih,
                                   dec_w_ih, fc_w, emb, y,
                                   wT2e, wT2d, w1b, w2b, wihb, dwihb, fcwb, adec);
  conv1_k<<<512, 256, 0, stream>>>(x, w1b, conv1_b, in1b);
  conv2_k<<<1024, 256, 71168, stream>>>(in1b, w2b, conv2_b, hbf);
  gemm_k<<<dim3(63, 6), 256, 0, stream>>>(hbf, wihb, rnn_b_ih, xge, 4000, 384, 544);
  gemm_k<<<dim3(64, 6), 256, 0, stream>>>(adec, dwihb, dec_b_ih, xgd, 4064, 384, 32);
  enc_k<<<32, 512, 0, stream>>>(wT2e, xge, rnn_b_hh, (u16*)ehb_k, (u16*)ehb_t);
  dec_k<<<32, 256, 35856, stream>>>(wT2d, ehb_k, ehb_t, xgd, dec_b_hh, h_init, outb);
  fc_k<<<dim3(32, 64), 256, 0, stream>>>(outb, fcwb, fc_b, logits);
}

// Round 17
// 504.497 us; speedup vs baseline: 1.0347x; 1.0347x over previous
//
#include <hip/hip_runtime.h>
#include <stdint.h>

typedef unsigned short u16;
typedef uint32_t u32;

typedef __bf16 bf16x8 __attribute__((ext_vector_type(8)));
typedef float f32x4 __attribute__((ext_vector_type(4)));
typedef _Float16 h2v __attribute__((ext_vector_type(2)));

union B8 { uint4 q; u32 u[4]; bf16x8 v; };

__device__ __forceinline__ u16 f2bf(float f) {
  u32 u = __float_as_uint(f);
  u32 r = (u + 0x7fffu + ((u >> 16) & 1u)) >> 16;
  return (u16)r;
}
__device__ __forceinline__ u16 f2h(float f) {
  union { _Float16 h; u16 u; } v; v.h = (_Float16)f; return v.u;
}
__device__ __forceinline__ float dot2h(u32 a, u32 b, float c) {
  union U { u32 u; h2v v; } A, B; A.u = a; B.u = b;
  return __builtin_amdgcn_fdot2(A.v, B.v, c, false);
}
__device__ __forceinline__ float sigf(float x) { return 1.f / (1.f + __expf(-x)); }
__device__ __forceinline__ float tanhf_fast(float x) {
  x = fminf(fmaxf(x, -15.f), 15.f);
  float e = __expf(2.f * x);
  return (e - 1.f) / (e + 1.f);
}

// ---------------- prep: pack/convert all weights (grid-stride x4) ----------------
__device__ __forceinline__ void prep_one(int e,
    const float* rnn_w_hh, const float* dec_w_hh, const float* conv1_w,
    const float* conv2_w, const float* rnn_w_ih, const float* dec_w_ih,
    const float* fc_w, const float* emb, const int* y,
    u32* wT2e, u32* wT2d, u16* w1b, u16* w2b, u16* wihb, u16* dwihb,
    u16* fcwb, u16* adec)
{
  const int S0 = 24576, S1 = 24576, S2 = 5120, S3 = 163840, S4 = 208896,
            S5 = 12288, S6 = 524288, S7 = 130048;
  if (e < S0) { int g = e >> 6, k2 = e & 63;
    wT2e[e] = (u32)f2h(rnn_w_hh[g*128 + 2*k2]) | ((u32)f2h(rnn_w_hh[g*128 + 2*k2 + 1]) << 16);
    return; }
  e -= S0;
  if (e < S1) { int g = e >> 6, k2 = e & 63;
    wT2d[e] = (u32)f2h(dec_w_hh[g*128 + 2*k2]) | ((u32)f2h(dec_w_hh[g*128 + 2*k2 + 1]) << 16);
    return; }
  e -= S1;
  if (e < S2) { int kh = e >> 10, c = (e >> 5) & 31, kw = e & 31;
    w1b[e] = f2bf(conv1_w[c*160 + kh*32 + kw]); return; }
  e -= S2;
  if (e < S3) { int kt = e >> 10, c = (e >> 5) & 31, kw = e & 31;
    int ic = kt / 5, kh = kt - ic * 5;
    w2b[e] = f2bf(conv2_w[((c*32 + ic)*5 + kh)*32 + kw]); return; }
  e -= S3;
  if (e < S4) { wihb[e] = f2bf(rnn_w_ih[e]); return; }
  e -= S4;
  if (e < S5) { dwihb[e] = f2bf(dec_w_ih[e]); return; }
  e -= S5;
  if (e < S6) { fcwb[e] = f2bf(fc_w[e]); return; }
  e -= S6;
  if (e < S7) { int m = e >> 5, k = e & 31;
    int b = m / 127, t = m - b * 127;
    adec[e] = f2bf(emb[y[b*128 + t]*32 + k]); return; }
}

__global__ __launch_bounds__(256) void prep_k(
    const float* rnn_w_hh, const float* dec_w_hh, const float* conv1_w,
    const float* conv2_w, const float* rnn_w_ih, const float* dec_w_ih,
    const float* fc_w, const float* emb, const int* y,
    u32* wT2e, u32* wT2d, u16* w1b, u16* w2b, u16* wihb, u16* dwihb,
    u16* fcwb, u16* adec)
{
  int e0 = blockIdx.x * 256 + threadIdx.x;
  #pragma unroll
  for (int it = 0; it < 4; it++) {
    int e = e0 + it * 273408;
    if (e < 1093632)
      prep_one(e, rnn_w_hh, dec_w_hh, conv1_w, conv2_w, rnn_w_ih, dec_w_ih,
               fc_w, emb, y, wT2e, wT2d, w1b, w2b, wihb, dwihb, fcwb, adec);
  }
}

// ---------------- conv1: (32,1,512,161) -> in1b (32,32,254,72pad) bf16, MFMA ----------------
__global__ __launch_bounds__(256) void conv1_k(const float* x, const u16* w1b,
                                               const float* c1b, u16* in1b)
{
  __shared__ __align__(16) u16 slab[35 * 162];
  __shared__ __align__(16) u16 wl[5120];
  int b = blockIdx.x >> 4;
  int oh0 = (blockIdx.x & 15) * 16;
  int ih0 = oh0 * 2;
  for (int e = threadIdx.x; e < 35 * 161; e += 256) {
    int r = e / 161, iw = e - r * 161;
    int ih = ih0 + r;
    float v = (ih < 512) ? x[(b*512 + ih)*161 + iw] : 0.f;
    slab[r*162 + iw] = f2bf(v);
  }
  for (int e = threadIdx.x; e < 5120; e += 256) wl[e] = w1b[e];
  __syncthreads();
  int lane = threadIdx.x & 63, wid = threadIdx.x >> 6;
  int lrow = lane & 15, lk = (lane >> 4) * 8;
  B8 bw[5][2];
  #pragma unroll
  for (int kt = 0; kt < 5; kt++)
    #pragma unroll
    for (int ct = 0; ct < 2; ct++)
      bw[kt][ct].q = *(const uint4*)&wl[(kt*32 + ct*16 + lrow)*32 + lk];
  float bias0 = c1b[lrow], bias1 = c1b[16 + lrow];
  for (int mt = wid; mt < 65; mt += 4) {
    int m = mt * 16 + lrow;
    int ohl = m / 65, ow = m - ohl * 65;
    int ro = ohl * 324 + ow * 2 + lk;
    f32x4 a0, a1;
    #pragma unroll
    for (int i = 0; i < 4; i++) { a0[i] = 0.f; a1[i] = 0.f; }
    #pragma unroll
    for (int kt = 0; kt < 5; kt++) {
      B8 af;
      const u32* p = (const u32*)&slab[ro + kt * 162];
      af.u[0] = p[0]; af.u[1] = p[1]; af.u[2] = p[2]; af.u[3] = p[3];
      a0 = __builtin_amdgcn_mfma_f32_16x16x32_bf16(af.v, bw[kt][0].v, a0, 0, 0, 0);
      a1 = __builtin_amdgcn_mfma_f32_16x16x32_bf16(af.v, bw[kt][1].v, a1, 0, 0, 0);
    }
    int rb = mt * 16 + (lane >> 4) * 4;
    #pragma unroll
    for (int i = 0; i < 4; i++) {
      int mr = rb + i;
      int ohl2 = mr / 65, ow2 = mr - ohl2 * 65;
      int oh = oh0 + ohl2;
      if (oh < 254) {
        float v0 = fmaxf(a0[i] + bias0, 0.f);
        float v1 = fmaxf(a1[i] + bias1, 0.f);
        in1b[((b*32 + lrow)*254 + oh)*72 + ow2] = f2bf(v0);
        in1b[((b*32 + 16 + lrow)*254 + oh)*72 + ow2] = f2bf(v1);
      }
    }
  }
}

// ---------------- conv2: in1b (32,32,254,72) -> h (32,125,544) bf16, MFMA ----------------
__global__ __launch_bounds__(256) void conv2_k(const u16* in1b, const u16* w2b,
                                               const float* c2b, u16* hbf)
{
  extern __shared__ char smem[];
  u16* slab = (u16*)smem;              // [32][11][72]  = 50688 B
  u16* wl = (u16*)(smem + 50688);      // [10][32][32]  = 20480 B
  int b = blockIdx.x >> 5;
  int tile = blockIdx.x & 31;
  int oh0 = tile * 4;
  int ih0 = oh0 * 2;
  for (int q = threadIdx.x; q < 3168; q += 256) {
    int ic = q / 99;
    int rem = q - ic * 99;
    int r = rem / 9, j = rem - r * 9;
    int ih = ih0 + r;
    uint4 v = make_uint4(0u, 0u, 0u, 0u);
    if (ih < 254) v = *(const uint4*)&in1b[(((b*32 + ic)*254 + ih)*72) + j*8];
    *(uint4*)&slab[(ic*11 + r)*72 + j*8] = v;
  }
  int lane = threadIdx.x & 63, wid = threadIdx.x >> 6;
  int lrow = lane & 15, lk = (lane >> 4) * 8;
  int ohl_[2], ow_[2];
  #pragma unroll
  for (int q = 0; q < 2; q++) {
    int mt = (q == 1) ? 4 : wid;
    int m = mt * 16 + lrow;
    if (m > 67) m = 0;
    ohl_[q] = m / 17; ow_[q] = m - ohl_[q] * 17;
  }
  f32x4 acc[2][2];
  #pragma unroll
  for (int q = 0; q < 2; q++)
    #pragma unroll
    for (int ct = 0; ct < 2; ct++)
      #pragma unroll
      for (int i = 0; i < 4; i++) acc[q][ct][i] = 0.f;

  for (int ph = 0; ph < 16; ph++) {
    __syncthreads();
    {
      const uint4* s4 = (const uint4*)&w2b[ph * 10240];
      uint4* d4 = (uint4*)wl;
      for (int q = threadIdx.x; q < 1280; q += 256) d4[q] = s4[q];
    }
    __syncthreads();
    for (int ktl = 0; ktl < 10; ktl++) {
      int ktg = ph * 10 + ktl;
      int ic = ktg / 5, kh = ktg - ic * 5;
      B8 fb0, fb1;
      fb0.q = *(const uint4*)&wl[(ktl*32 + lrow)*32 + lk];
      fb1.q = *(const uint4*)&wl[(ktl*32 + 16 + lrow)*32 + lk];
      int base = (ic * 11 + kh) * 72 + lk;
      #pragma unroll
      for (int q = 0; q < 2; q++) {
        if (q == 1 && wid != 0) break;
        B8 af;
        const u32* p = (const u32*)&slab[base + ohl_[q] * 144 + ow_[q] * 2];
        af.u[0] = p[0]; af.u[1] = p[1]; af.u[2] = p[2]; af.u[3] = p[3];
        acc[q][0] = __builtin_amdgcn_mfma_f32_16x16x32_bf16(af.v, fb0.v, acc[q][0], 0, 0, 0);
        acc[q][1] = __builtin_amdgcn_mfma_f32_16x16x32_bf16(af.v, fb1.v, acc[q][1], 0, 0, 0);
      }
    }
  }
  #pragma unroll
  for (int q = 0; q < 2; q++) {
    if (q == 1 && wid != 0) break;
    int mt = (q == 1) ? 4 : wid;
    int rb = mt * 16 + (lane >> 4) * 4;
    #pragma unroll
    for (int ct = 0; ct < 2; ct++) {
      int c = ct * 16 + lrow;
      float bias = c2b[c];
      #pragma unroll
      for (int i = 0; i < 4; i++) {
        int mr = rb + i;
        if (mr < 68) {
          int ohl = mr / 17, ow = mr - ohl * 17;
          int oh = oh0 + ohl;
          if (oh < 125) {
            float v = fmaxf(acc[q][ct][i] + bias, 0.f);
            hbf[(b*125 + oh)*544 + ow*32 + c] = f2bf(v);
          }
        }
      }
    }
  }
}

// ---------------- generic bf16 MFMA GEMM: C = A(MxK) * B(NxK)^T + bias ----------------
__global__ __launch_bounds__(256) void gemm_k(const u16* A, const u16* Bw,
                                              const float* bias, float* C,
                                              int M, int N, int K)
{
  __shared__ __align__(16) u16 As[64 * 32];
  __shared__ __align__(16) u16 Bs[64 * 32];
  int m0 = blockIdx.x * 64, n0 = blockIdx.y * 64;
  int tid = threadIdx.x;
  int lane = tid & 63, wid = tid >> 6;
  int lrow = lane & 15, lk = (lane >> 4) * 8;
  int sr = tid >> 2, sc8 = (tid & 3) * 8;
  f32x4 acc[4];
  #pragma unroll
  for (int nt = 0; nt < 4; nt++)
    #pragma unroll
    for (int i = 0; i < 4; i++) acc[nt][i] = 0.f;
  int nkt = K >> 5;
  for (int kt = 0; kt < nkt; kt++) {
    __syncthreads();
    uint4 va = make_uint4(0u, 0u, 0u, 0u);
    int arow = m0 + sr;
    if (arow < M) va = *(const uint4*)&A[arow * K + kt * 32 + sc8];
    *(uint4*)&As[sr * 32 + sc8] = va;
    uint4 vb = *(const uint4*)&Bw[(n0 + sr) * K + kt * 32 + sc8];
    *(uint4*)&Bs[sr * 32 + sc8] = vb;
    __syncthreads();
    B8 af; af.q = *(const uint4*)&As[(wid * 16 + lrow) * 32 + lk];
    #pragma unroll
    for (int nt = 0; nt < 4; nt++) {
      B8 bb; bb.q = *(const uint4*)&Bs[(nt * 16 + lrow) * 32 + lk];
      acc[nt] = __builtin_amdgcn_mfma_f32_16x16x32_bf16(af.v, bb.v, acc[nt], 0, 0, 0);
    }
  }
  #pragma unroll
  for (int nt = 0; nt < 4; nt++) {
    int col = n0 + nt * 16 + lrow;
    float bv = bias[col];
    #pragma unroll
    for (int i = 0; i < 4; i++) {
      int row = m0 + wid * 16 + (lane >> 4) * 4 + i;
      if (row < M) C[row * N + col] = acc[nt][i] + bv;
    }
  }
}

// ---------------- fc GEMM: 4096x4096, K=128, 128x64 tile ----------------
__global__ __launch_bounds__(256) void fc_k(const u16* A, const u16* Bw,
                                            const float* bias, float* C)
{
  __shared__ __align__(16) u16 As[128 * 32];
  __shared__ __align__(16) u16 Bs[64 * 32];
  int m0 = blockIdx.x * 128, n0 = blockIdx.y * 64;
  int tid = threadIdx.x;
  int lane = tid & 63, wid = tid >> 6;
  int lrow = lane & 15, lk = (lane >> 4) * 8;
  f32x4 acc[2][4];
  #pragma unroll
  for (int mq = 0; mq < 2; mq++)
    #pragma unroll
    for (int nt = 0; nt < 4; nt++)
      #pragma unroll
      for (int i = 0; i < 4; i++) acc[mq][nt][i] = 0.f;
  #pragma unroll
  for (int kt = 0; kt < 4; kt++) {
    __syncthreads();
    #pragma unroll
    for (int i = tid; i < 512; i += 256) {
      int row = i >> 2, q = i & 3;
      *(uint4*)&As[row * 32 + q * 8] = *(const uint4*)&A[(m0 + row) * 128 + kt * 32 + q * 8];
    }
    {
      int row = tid >> 2, q = tid & 3;
      *(uint4*)&Bs[row * 32 + q * 8] = *(const uint4*)&Bw[(n0 + row) * 128 + kt * 32 + q * 8];
    }
    __syncthreads();
    B8 bb[4];
    #pragma unroll
    for (int nt = 0; nt < 4; nt++) bb[nt].q = *(const uint4*)&Bs[(nt * 16 + lrow) * 32 + lk];
    #pragma unroll
    for (int mq = 0; mq < 2; mq++) {
      B8 af; af.q = *(const uint4*)&As[((wid * 2 + mq) * 16 + lrow) * 32 + lk];
      #pragma unroll
      for (int nt = 0; nt < 4; nt++)
        acc[mq][nt] = __builtin_amdgcn_mfma_f32_16x16x32_bf16(af.v, bb[nt].v, acc[mq][nt], 0, 0, 0);
    }
  }
  #pragma unroll
  for (int nt = 0; nt < 4; nt++) {
    int col = n0 + nt * 16 + lrow;
    float bv = bias[col];
    #pragma unroll
    for (int mq = 0; mq < 2; mq++)
      #pragma unroll
      for (int i = 0; i < 4; i++) {
        int row = m0 + (wid * 2 + mq) * 16 + (lane >> 4) * 4 + i;
        C[(size_t)row * 4096 + col] = acc[mq][nt][i] + bv;
      }
  }
}

// ---------------- encoder GRU scan: 32 blocks, 512 thr, 1 batch, K-split 4 ----------------
__global__ __launch_bounds__(512, 1) void enc_k(const u32* wT2, const float* xg,
                                                const float* bhh_g, u16* ehk, u16* eht)
{
  __shared__ __align__(16) u32 hp[2][64];      // [buf][64]
  __shared__ float hg[1152];                   // [kh-1][gate][128]
  int tid = threadIdx.x;
  int kh = tid >> 7, t = tid & 127;
  int b = blockIdx.x;
  u32 w0[16], w1[16], w2[16];
  {
    const uint4* p0 = (const uint4*)(wT2 + (size_t)t * 64 + kh * 16);
    const uint4* p1 = (const uint4*)(wT2 + (size_t)(128 + t) * 64 + kh * 16);
    const uint4* p2 = (const uint4*)(wT2 + (size_t)(256 + t) * 64 + kh * 16);
    #pragma unroll
    for (int j = 0; j < 4; j++) {
      uint4 q0 = p0[j]; w0[4*j] = q0.x; w0[4*j+1] = q0.y; w0[4*j+2] = q0.z; w0[4*j+3] = q0.w;
      uint4 q1 = p1[j]; w1[4*j] = q1.x; w1[4*j+1] = q1.y; w1[4*j+2] = q1.z; w1[4*j+3] = q1.w;
      uint4 q2 = p2[j]; w2[4*j] = q2.x; w2[4*j+1] = q2.y; w2[4*j+2] = q2.z; w2[4*j+3] = q2.w;
    }
  }
  float b0 = 0.f, b1 = 0.f, b2 = 0.f, xr0 = 0.f, xr1 = 0.f, xr2 = 0.f, hreg = 0.f;
  if (kh == 0) {
    b0 = bhh_g[t]; b1 = bhh_g[128 + t]; b2 = bhh_g[256 + t];
    const float* xp = &xg[(size_t)b * 125 * 384];
    xr0 = xp[t]; xr1 = xp[128 + t]; xr2 = xp[256 + t];
    ((u16*)&hp[0][0])[t] = 0;
  }
  __syncthreads();
  for (int tt = 0; tt < 125; tt++) {
    const u32* hb = &hp[tt & 1][kh * 16];
    float r0 = 0.f, r1 = 0.f, z0 = 0.f, z1 = 0.f, n0 = 0.f, n1 = 0.f;
    #pragma unroll
    for (int j = 0; j < 4; j++) {
      uint4 hv = *(const uint4*)&hb[4*j];
      r0 = dot2h(w0[4*j+0], hv.x, r0); r1 = dot2h(w0[4*j+1], hv.y, r1);
      r0 = dot2h(w0[4*j+2], hv.z, r0); r1 = dot2h(w0[4*j+3], hv.w, r1);
      z0 = dot2h(w1[4*j+0], hv.x, z0); z1 = dot2h(w1[4*j+1], hv.y, z1);
      z0 = dot2h(w1[4*j+2], hv.z, z0); z1 = dot2h(w1[4*j+3], hv.w, z1);
      n0 = dot2h(w2[4*j+0], hv.x, n0); n1 = dot2h(w2[4*j+1], hv.y, n1);
      n0 = dot2h(w2[4*j+2], hv.z, n0); n1 = dot2h(w2[4*j+3], hv.w, n1);
    }
    if (kh) {
      float* hh = &hg[(kh - 1) * 384];
      hh[t] = r0 + r1; hh[128 + t] = z0 + z1; hh[256 + t] = n0 + n1;
    }
    __syncthreads();
    if (kh == 0) {
      const float* hh = &hg[0];
      float pr = r0 + r1 + hh[t] + hh[384 + t] + hh[768 + t];
      float pz = z0 + z1 + hh[128 + t] + hh[512 + t] + hh[896 + t];
      float pn = n0 + n1 + hh[256 + t] + hh[640 + t] + hh[1024 + t];
      float r = sigf(xr0 + pr + b0);
      float z = sigf(xr1 + pz + b1);
      float n = tanhf_fast(xr2 + r * (pn + b2));
      hreg = (1.f - z) * n + z * hreg;
      u16 hv = f2h(hreg);
      ((u16*)&hp[(tt & 1) ^ 1][0])[t] = hv;
      ehk[((size_t)(b*64 + (t >> 1)) * 125 + tt) * 2 + (t & 1)] = hv;
      eht[((size_t)(b*128 + t)) * 128 + tt] = hv;
      if (tt + 1 < 125) {
        const float* xq = &xg[((size_t)b * 125 + tt + 1) * 384];
        xr0 = xq[t]; xr1 = xq[128 + t]; xr2 = xq[256 + t];
      }
    }
    __syncthreads();
  }
  if (kh == 0) {
    size_t rb = ((size_t)(b*128 + t)) * 128;
    eht[rb + 125] = 0; eht[rb + 126] = 0; eht[rb + 127] = 0;
  }
}

// ---------------- decoder GRU + attention: 32 blocks, 512 thr, 1 batch, K-split 4 ----------------
// (verified 236 us configuration from round 15)
__global__ __launch_bounds__(512, 1) void dec_k(const u32* wT2, const u32* ehk_g,
                                                const u32* eht_g, const float* xgd,
                                                const float* bhh_g, const float* h_init,
                                                u16* outb)
{
  extern __shared__ char sm[];
  int tid = threadIdx.x;
  int kh = tid >> 7, t = tid & 127;
  int b = blockIdx.x;
  char* base = sm;
  u32* elK   = (u32*)base;                    // [64][125]
  float* hgP = (float*)(base + 32000);        // [3][3][128]
  float* sp  = (float*)(base + 36608);        // [4][128]
  float* ctxB= (float*)(base + 38656);        // [3][128]
  u16* hxA   = (u16*)(base + 40192);
  u16* hxB   = (u16*)(base + 40448);
  u16* scp   = (u16*)(base + 40704);
  float* red = (float*)(base + 40960);

  u32 w0[16], w1[16], w2[16];
  {
    const uint4* p0 = (const uint4*)(wT2 + (size_t)t * 64 + kh * 16);
    const uint4* p1 = (const uint4*)(wT2 + (size_t)(128 + t) * 64 + kh * 16);
    const uint4* p2 = (const uint4*)(wT2 + (size_t)(256 + t) * 64 + kh * 16);
    #pragma unroll
    for (int j = 0; j < 4; j++) {
      uint4 q0 = p0[j]; w0[4*j] = q0.x; w0[4*j+1] = q0.y; w0[4*j+2] = q0.z; w0[4*j+3] = q0.w;
      uint4 q1 = p1[j]; w1[4*j] = q1.x; w1[4*j+1] = q1.y; w1[4*j+2] = q1.z; w1[4*j+3] = q1.w;
      uint4 q2 = p2[j]; w2[4*j] = q2.x; w2[4*j+1] = q2.y; w2[4*j+2] = q2.z; w2[4*j+3] = q2.w;
    }
  }
  // context operand: unit-row t, K-quarter kh of eh^T  (step-constant, 16 u32)
  u32 rowr[16];
  {
    const uint4* rp = (const uint4*)(eht_g + (size_t)b * 8192 + (size_t)t * 64 + kh * 16);
    #pragma unroll
    for (int j = 0; j < 4; j++) {
      uint4 q = rp[j]; rowr[4*j] = q.x; rowr[4*j+1] = q.y; rowr[4*j+2] = q.z; rowr[4*j+3] = q.w;
    }
  }
  for (int e = tid; e < 8000; e += 512) elK[e] = ehk_g[(size_t)b * 8000 + e];
  float b0 = 0.f, b1 = 0.f, b2 = 0.f, xr0 = 0.f, xr1 = 0.f, xr2 = 0.f;
  float hxf = 0.f, hxg = 0.f;
  if (kh == 0) {
    b0 = bhh_g[t]; b1 = bhh_g[128 + t]; b2 = bhh_g[256 + t];
    hxf = h_init[t];
    const float* xp = &xgd[(size_t)b * 127 * 384];
    xr0 = xp[t]; xr1 = xp[128 + t]; xr2 = xp[256 + t];
  }
  __syncthreads();

  for (int step = 0; step < 128; step++) {
    if (step > 0) {
      // ---- S0: GRU quarter-K dots (all 512 thr) ----
      const u32* hb = (const u32*)hxB + kh * 16;
      float r0 = 0.f, r1 = 0.f, z0 = 0.f, z1 = 0.f, n0 = 0.f, n1 = 0.f;
      #pragma unroll
      for (int j = 0; j < 4; j++) {
        uint4 hv = *(const uint4*)&hb[4*j];
        r0 = dot2h(w0[4*j+0], hv.x, r0); r1 = dot2h(w0[4*j+1], hv.y, r1);
        r0 = dot2h(w0[4*j+2], hv.z, r0); r1 = dot2h(w0[4*j+3], hv.w, r1);
        z0 = dot2h(w1[4*j+0], hv.x, z0); z1 = dot2h(w1[4*j+1], hv.y, z1);
        z0 = dot2h(w1[4*j+2], hv.z, z0); z1 = dot2h(w1[4*j+3], hv.w, z1);
        n0 = dot2h(w2[4*j+0], hv.x, n0); n1 = dot2h(w2[4*j+1], hv.y, n1);
        n0 = dot2h(w2[4*j+2], hv.z, n0); n1 = dot2h(w2[4*j+3], hv.w, n1);
      }
      if (kh) {
        float* hh = &hgP[(kh - 1) * 384];
        hh[t] = r0 + r1; hh[128 + t] = z0 + z1; hh[256 + t] = n0 + n1;
      }
      __syncthreads();                       // bar1
      if (kh == 0) {
        float pr = r0 + r1 + hgP[t] + hgP[384 + t] + hgP[768 + t];
        float pz = z0 + z1 + hgP[128 + t] + hgP[512 + t] + hgP[896 + t];
        float pn = n0 + n1 + hgP[256 + t] + hgP[640 + t] + hgP[1024 + t];
        float r = sigf(xr0 + pr + b0);
        float z = sigf(xr1 + pz + b1);
        float n = tanhf_fast(xr2 + r * (pn + b2));
        hxg = (1.f - z) * n + z * hxf;
        ((u16*)hxA)[t] = f2h(hxg);
        if (step < 127) {
          const float* xq = &xgd[((size_t)b * 127 + step) * 384];
          xr0 = xq[t]; xr1 = xq[128 + t]; xr2 = xq[256 + t];
        }
      }
      __syncthreads();                       // bar2
    } else {
      if (kh == 0) { hxg = hxf; ((u16*)hxA)[t] = f2h(hxg); }
      __syncthreads();                       // bar2
    }
    // ---- S2a: score quarter-K partials (all threads; t = time index) ----
    {
      float s0 = 0.f, s1 = 0.f;
      const u32* ek = &elK[(kh * 16) * 125];
      const u32* hxA4 = (const u32*)hxA;
      #pragma unroll
      for (int j = 0; j < 4; j++) {
        uint4 aw = *(const uint4*)&hxA4[kh * 16 + 4*j];
        s0 = dot2h(ek[(4*j+0)*125 + t], aw.x, s0);
        s1 = dot2h(ek[(4*j+1)*125 + t], aw.y, s1);
        s0 = dot2h(ek[(4*j+2)*125 + t], aw.z, s0);
        s1 = dot2h(ek[(4*j+3)*125 + t], aw.w, s1);
      }
      sp[kh * 128 + t] = s0 + s1;
    }
    __syncthreads();                         // bar3a
    // ---- S2b: combine + softmax (kh0; waves = t 0-63 / 64-127) ----
    if (kh == 0) {
      float s = (t < 125) ? (sp[t] + sp[128 + t] + sp[256 + t] + sp[384 + t]) : -1e30f;
      float mw = s;
      #pragma unroll
      for (int o = 32; o > 0; o >>= 1) mw = fmaxf(mw, __shfl_xor(mw, o));
      float ev = (t < 125) ? __expf(s - mw) : 0.f;
      float sw = ev;
      #pragma unroll
      for (int o = 32; o > 0; o >>= 1) sw += __shfl_xor(sw, o);
      ((u16*)scp)[t] = f2h(ev);
      if ((t & 63) == 0) { int wv = t >> 6; red[wv*2] = mw; red[wv*2 + 1] = sw; }
    }
    __syncthreads();                         // bar3
    // ---- S3: context quarter-T dots (all threads; t = unit index) ----
    float m0r = red[0], S0r = red[1], m1r = red[2], S1r = red[3];
    float M = fmaxf(m0r, m1r);
    float f0 = __expf(m0r - M), f1 = __expf(m1r - M);
    float inv = 1.f / (f0 * S0r + f1 * S1r);
    float c0 = 0.f, c1 = 0.f;
    {
      const u32* scp4 = (const u32*)scp;
      #pragma unroll
      for (int j = 0; j < 4; j++) {
        uint4 sw4 = *(const uint4*)&scp4[kh * 16 + 4*j];
        c0 = dot2h(rowr[4*j+0], sw4.x, c0); c1 = dot2h(rowr[4*j+1], sw4.y, c1);
        c0 = dot2h(rowr[4*j+2], sw4.z, c0); c1 = dot2h(rowr[4*j+3], sw4.w, c1);
      }
    }
    if (kh) ctxB[(kh - 1) * 128 + t] = c0 + c1;
    __syncthreads();                         // bar4
    if (kh == 0) {
      // kh 0,1 cover t<64 (wave0 scale f0); kh 2,3 cover t>=64 (f1)
      float ctx = ((c0 + c1) + ctxB[t]) * f0 + (ctxB[128 + t] + ctxB[256 + t]) * f1;
      hxf = hxg + ctx * inv;
      outb[((size_t)(b * 128) + step) * 128 + t] = f2bf(hxf);
      ((u16*)hxB)[t] = f2h(hxf);
    }
    __syncthreads();                         // bar5
  }
}

// ---------------- host launch ----------------
extern "C" void kernel_launch(void* const* d_in, const int* in_sizes, int n_in,
                              void* d_out, int out_size, void* d_ws, size_t ws_size,
                              hipStream_t stream)
{
  const float* x        = (const float*)d_in[0];
  const int*   y        = (const int*)d_in[1];
  const float* conv1_w  = (const float*)d_in[2];
  const float* conv1_b  = (const float*)d_in[3];
  const float* conv2_w  = (const float*)d_in[4];
  const float* conv2_b  = (const float*)d_in[5];
  const float* rnn_w_ih = (const float*)d_in[6];
  const float* rnn_w_hh = (const float*)d_in[7];
  const float* rnn_b_ih = (const float*)d_in[8];
  const float* rnn_b_hh = (const float*)d_in[9];
  const float* emb      = (const float*)d_in[10];
  const float* dec_w_ih = (const float*)d_in[11];
  const float* dec_w_hh = (const float*)d_in[12];
  const float* dec_b_ih = (const float*)d_in[13];
  const float* dec_b_hh = (const float*)d_in[14];
  const float* fc_w     = (const float*)d_in[15];
  const float* fc_b     = (const float*)d_in[16];
  const float* h_init   = (const float*)d_in[17];
  float* logits = (float*)d_out;

  char* ws = (char*)d_ws;
  size_t off = 0;
  auto alloc = [&](size_t bytes) { char* p = ws + off; off = (off + bytes + 255) & ~(size_t)255; return p; };
  u16* in1b  = (u16*)alloc(37453824);  // conv1 out bf16 (32,32,254,72pad)
  u16* hbf   = (u16*)alloc(4352000);   // h bf16 (4000,544)
  float* xge = (float*)alloc(6144000); // enc xg (4000,384)
  u32* ehb_k = (u32*)alloc(1024000);   // eh f16 k-pairs (32,64,125)
  u32* ehb_t = (u32*)alloc(1048576);   // eh f16 t-pair rows (32,128,64)
  float* xgd = (float*)alloc(6242304); // dec xg (4064,384)
  u16* adec  = (u16*)alloc(260096);    // emb gather (4064,32)
  u16* outb  = (u16*)alloc(1048576);   // decoder out bf16 (4096,128)
  u32* wT2e  = (u32*)alloc(98304);
  u32* wT2d  = (u32*)alloc(98304);
  u16* w1b   = (u16*)alloc(10240);
  u16* w2b   = (u16*)alloc(327680);
  u16* wihb  = (u16*)alloc(417792);
  u16* dwihb = (u16*)alloc(24576);
  u16* fcwb  = (u16*)alloc(1048576);

  hipFuncSetAttribute((const void*)conv2_k, hipFuncAttributeMaxDynamicSharedMemorySize, 71168);
  hipFuncSetAttribute((const void*)dec_k,   hipFuncAttributeMaxDynamicSharedMemorySize, 41024);

  prep_k<<<1068, 256, 0, stream>>>(rnn_w_hh, dec_w_hh, conv1_w, conv2_w, rnn_w_ih,
                                   dec_w_ih, fc_w, emb, y,
                                   wT2e, wT2d, w1b, w2b, wihb, dwihb, fcwb, adec);
  conv1_k<<<512, 256, 0, stream>>>(x, w1b, conv1_b, in1b);
  conv2_k<<<1024, 256, 71168, stream>>>(in1b, w2b, conv2_b, hbf);
  gemm_k<<<dim3(63, 6), 256, 0, stream>>>(hbf, wihb, rnn_b_ih, xge, 4000, 384, 544);
  gemm_k<<<dim3(64, 6), 256, 0, stream>>>(adec, dwihb, dec_b_ih, xgd, 4064, 384, 32);
  enc_k<<<32, 512, 0, stream>>>(wT2e, xge, rnn_b_hh, (u16*)ehb_k, (u16*)ehb_t);
  dec_k<<<32, 512, 41024, stream>>>(wT2d, ehb_k, ehb_t, xgd, dec_b_hh, h_init, outb);
  fc_k<<<dim3(32, 64), 256, 0, stream>>>(outb, fcwb, fc_b, logits);
}